// Round 14
// baseline (338.411 us; speedup 1.0000x reference)
//
#include <hip/hip_runtime.h>
#include <cstdint>
#include <cstddef>

#define DD 128
#define KK 32
constexpr float EPS = 1e-8f;

typedef __bf16 bf16x8 __attribute__((ext_vector_type(8)));
typedef float f32x4 __attribute__((ext_vector_type(4)));

__device__ __forceinline__ unsigned short f2bf(float x) {
    union { float f; uint32_t u; } v; v.f = x;
    uint32_t r = v.u + 0x7FFFu + ((v.u >> 16) & 1u);   // RNE
    return (unsigned short)(r >> 16);
}
// pack 8 floats -> 8 bf16 in a uint4 (one 16B store)
__device__ __forceinline__ uint4 pack8(float4 a, float4 b) {
    uint4 o;
    o.x = (uint32_t)f2bf(a.x) | ((uint32_t)f2bf(a.y) << 16);
    o.y = (uint32_t)f2bf(a.z) | ((uint32_t)f2bf(a.w) << 16);
    o.z = (uint32_t)f2bf(b.x) | ((uint32_t)f2bf(b.y) << 16);
    o.w = (uint32_t)f2bf(b.z) | ((uint32_t)f2bf(b.w) << 16);
    return o;
}

// DPP quad_perm fold over lane-xor 1,2 (VALU pipe, no LDS).
template <int CTRL>
__device__ __forceinline__ float dpp_fold(float x) {
    union { float f; int i; } u, r;
    u.f = x;
    r.i = __builtin_amdgcn_update_dpp(0, u.i, CTRL, 0xF, 0xF, false);
    return x + r.f;
}
__device__ __forceinline__ f32x4 fold4(f32x4 v) {
    #pragma unroll
    for (int c = 0; c < 4; ++c) {
        float x = v[c];
        x = dpp_fold<0xB1>(x);   // xor 1
        x = dpp_fold<0x4E>(x);   // xor 2
        v[c] = x;
    }
    return v;
}

// ---------------- prep kernel: cvt (LDS-transposed) + wf + part2 ------------
// Xf[rg][c][mm][8]: row = rg*16+mm, d = c*8+j  -> off = rg*2048 + c*128 + mm*8
// Wf[k][eg][c][mm][8]: W[k][d=c*8+j][e=eg*16+mm]
// part2 branch reads RAW fp32 x1/x2 + V (no dependency on Xf -> no race):
//   p2w[n][k] = x1[n].V[k][0:128] + x2[n].V[k][128:256]
__global__ __launch_bounds__(256) void prep_kernel(
    const float* __restrict__ x1, const float* __restrict__ x2,
    const float* __restrict__ W1, const float* __restrict__ W2,
    const float* __restrict__ V,
    __bf16* __restrict__ X1f, __bf16* __restrict__ X2f,
    __bf16* __restrict__ W1f, __bf16* __restrict__ W2f,
    float* __restrict__ p2w,
    int cvt_half, int wf_half)
{
    __shared__ float tile[16][132];   // 8.4 KB, +4 pad
    int bb = blockIdx.x;
    if (bb < 2 * cvt_half) {
        // one block = 16 rows (one rg) of one tensor
        const float* src; __bf16* dst;
        if (bb >= cvt_half) { src = x2; dst = X2f; bb -= cvt_half; }
        else                { src = x1; dst = X1f; }
        const int rg = bb;
        {
            const int row = threadIdx.x >> 4;
            const int c8  = (threadIdx.x & 15) * 8;
            const float* p = src + (size_t)(rg * 16 + row) * DD + c8;
            float4 f0 = *reinterpret_cast<const float4*>(p);
            float4 f1 = *reinterpret_cast<const float4*>(p + 4);
            *reinterpret_cast<float4*>(&tile[row][c8])     = f0;
            *reinterpret_cast<float4*>(&tile[row][c8 + 4]) = f1;
        }
        __syncthreads();
        {
            const int mm = threadIdx.x & 15;
            const int c  = threadIdx.x >> 4;
            float4 a = *reinterpret_cast<float4*>(&tile[mm][c * 8]);
            float4 b = *reinterpret_cast<float4*>(&tile[mm][c * 8 + 4]);
            size_t off = (size_t)rg * 2048 + (size_t)c * 128 + (size_t)mm * 8;
            *reinterpret_cast<uint4*>(dst + off) = pack8(a, b);
        }
    } else if (bb < 2 * cvt_half + 2 * wf_half) {
        bb -= 2 * cvt_half;
        const float* W; __bf16* Wf;
        if (bb >= wf_half) { W = W2; Wf = W2f; bb -= wf_half; }
        else               { W = W1; Wf = W1f; }
        int idx = bb * 256 + threadIdx.x;
        int mm = idx & 15;
        int c  = (idx >> 4) & 15;
        int eg = (idx >> 8) & 7;
        int k  = idx >> 11;
        const float* Wk = W + (size_t)k * DD * DD;
        int e = eg * 16 + mm;
        float4 a, b;
        a.x = Wk[(size_t)(c * 8 + 0) * DD + e];
        a.y = Wk[(size_t)(c * 8 + 1) * DD + e];
        a.z = Wk[(size_t)(c * 8 + 2) * DD + e];
        a.w = Wk[(size_t)(c * 8 + 3) * DD + e];
        b.x = Wk[(size_t)(c * 8 + 4) * DD + e];
        b.y = Wk[(size_t)(c * 8 + 5) * DD + e];
        b.z = Wk[(size_t)(c * 8 + 6) * DD + e];
        b.w = Wk[(size_t)(c * 8 + 7) * DD + e];
        size_t off = ((size_t)(k * 8 + eg)) * 2048 + (size_t)c * 128 + (size_t)mm * 8;
        *reinterpret_cast<uint4*>(Wf + off) = pack8(a, b);
    } else {
        // part2: block = 4 rows x 32 k x 2 halves. t = r*64 + k*2 + h.
        // V reads: thread streams 512 B at base t*512 within V[k] -> the block
        // collectively reads V fully contiguously. x reads broadcast via L1.
        int bb2 = bb - 2 * cvt_half - 2 * wf_half;
        const int r = threadIdx.x >> 6;
        const int k = (threadIdx.x >> 1) & 31;
        const int h = threadIdx.x & 1;
        const size_t n = (size_t)bb2 * 4 + r;
        const float* xp = (h ? x2 : x1) + n * DD;
        const float* vp = V + (size_t)k * 256 + h * DD;
        float s = 0.f;
        #pragma unroll
        for (int i = 0; i < 32; ++i) {
            float4 xa = *reinterpret_cast<const float4*>(xp + i * 4);
            float4 va = *reinterpret_cast<const float4*>(vp + i * 4);
            s += xa.x * va.x + xa.y * va.y + xa.z * va.z + xa.w * va.w;
        }
        s = dpp_fold<0xB1>(s);   // combine h=0/1 partners (adjacent lanes)
        if (h == 0) p2w[n * KK + k] = s;
    }
}

// ---------------- main fused kernel (r13 + round-robin output wave) ---------
// Grid 4096 = 32 k x 128 row-groups (256 rows). XCD decode: xcd=b&7,
// k=(b>>3)&31 fast, group per-XCD. Block = 4 waves, wave = (rh, eh):
// 16 rows x 64 cols of BOTH mats, B register-resident (unified VGPR/AGPR),
// A fragments prefetched one tile ahead. Tile g's final output runs on wave
// g&3 so the tail skew rotates instead of always stalling waves 1-3.
__global__ __launch_bounds__(256, 2) void ntn_main(
    const __bf16* __restrict__ X1f, const __bf16* __restrict__ X2f,
    const __bf16* __restrict__ W1f, const __bf16* __restrict__ W2f,
    const float* __restrict__ p2w, const float* __restrict__ bias,
    float* __restrict__ out, int grp_per_xcd)
{
    __shared__ __align__(16) float sRed[2][3][2][4][36];  // 13.8 KB

    const int b    = blockIdx.x;
    const int xcd  = b & 7;
    const int k    = (b >> 3) & 31;
    const int grpN = xcd * grp_per_xcd + (b >> 8);   // 256-row group
    const int tid  = threadIdx.x;
    const int wave = tid >> 6;
    const int lane = tid & 63;
    const int m    = lane & 15;
    const int quad = lane >> 4;
    const int rh   = wave & 1;      // row half of the 32-row tile
    const int eh   = wave >> 1;     // column half (64 cols)

    const __bf16* W1p = W1f + (size_t)k * 16384;
    const __bf16* W2p = W2f + (size_t)k * 16384;

    // ---- cache BOTH B halves in registers: 2 mats x 4 ks x 4 et ----
    bf16x8 Bc[2][4][4];
    #pragma unroll
    for (int ks = 0; ks < 4; ++ks)
        #pragma unroll
        for (int et = 0; et < 4; ++et) {
            const size_t boff = (size_t)(eh * 4 + et) * 2048 + ks * 512 + lane * 8;
            Bc[0][ks][et] = *reinterpret_cast<const bf16x8*>(W1p + boff);
            Bc[1][ks][et] = *reinterpret_cast<const bf16x8*>(W2p + boff);
        }

    const float bk = bias[k];
    const int rg0 = grpN * 16;
    const size_t lane8 = (size_t)lane * 8;

    // ---- preload tile 0's A fragments ----
    bf16x8 a1[4], a2[4];
    {
        const size_t ab = (size_t)(rg0 + rh) * 2048 + lane8;
        #pragma unroll
        for (int ks = 0; ks < 4; ++ks) {
            a1[ks] = *reinterpret_cast<const bf16x8*>(X1f + ab + ks * 512);
            a2[ks] = *reinterpret_cast<const bf16x8*>(X2f + ab + ks * 512);
        }
    }

    #pragma unroll
    for (int g = 0; g < 8; ++g) {
        f32x4 acc[2][4];    // [mat][et]
        #pragma unroll
        for (int mat = 0; mat < 2; ++mat)
            #pragma unroll
            for (int et = 0; et < 4; ++et) acc[mat][et] = f32x4{0.f, 0.f, 0.f, 0.f};

        #pragma unroll
        for (int ks = 0; ks < 4; ++ks) {
            #pragma unroll
            for (int et = 0; et < 4; ++et) {
                acc[0][et] = __builtin_amdgcn_mfma_f32_16x16x32_bf16(a1[ks], Bc[0][ks][et], acc[0][et], 0, 0, 0);
                acc[1][et] = __builtin_amdgcn_mfma_f32_16x16x32_bf16(a2[ks], Bc[1][ks][et], acc[1][et], 0, 0, 0);
            }
        }

        // ---- prefetch tile g+1's A fragments (fly through epilogue+barrier)
        if (g < 7) {
            const size_t ab = (size_t)(rg0 + (g + 1) * 2 + rh) * 2048 + lane8;
            #pragma unroll
            for (int ks = 0; ks < 4; ++ks) {
                a1[ks] = *reinterpret_cast<const bf16x8*>(X1f + ab + ks * 512);
                a2[ks] = *reinterpret_cast<const bf16x8*>(X2f + ab + ks * 512);
            }
        }

        // ---- in-register cross-mat epilogue + DPP folds ----
        f32x4 pd = {0.f, 0.f, 0.f, 0.f};
        f32x4 q1 = {0.f, 0.f, 0.f, 0.f};
        f32x4 q2 = {0.f, 0.f, 0.f, 0.f};
        #pragma unroll
        for (int et = 0; et < 4; ++et) {
            f32x4 c1 = acc[0][et];
            f32x4 c2 = acc[1][et];
            pd += c1 * c2;
            q1 += c1 * c1;
            q2 += c2 * c2;
        }
        pd = fold4(pd);
        q1 = fold4(q1);
        q2 = fold4(q2);

        const int buf = g & 1;
        if ((m & 3) == 0) {
            const int grp = m >> 2;
            const int rb  = rh * 16 + quad * 4;
            *reinterpret_cast<f32x4*>(&sRed[buf][0][eh][grp][rb]) = pd;
            *reinterpret_cast<f32x4*>(&sRed[buf][1][eh][grp][rb]) = q1;
            *reinterpret_cast<f32x4*>(&sRed[buf][2][eh][grp][rb]) = q2;
        }

        __syncthreads();   // sRed[buf] visible (next tile writes other buf)

        if (wave == (g & 3) && lane < 32) {
            const int row = lane;
            float dot = 0.f, s1 = 0.f, s2 = 0.f;
            #pragma unroll
            for (int e2 = 0; e2 < 2; ++e2)
                #pragma unroll
                for (int gg = 0; gg < 4; ++gg) {
                    dot += sRed[buf][0][e2][gg][row];
                    s1  += sRed[buf][1][e2][gg][row];
                    s2  += sRed[buf][2][e2][gg][row];
                }
            const size_t n = (size_t)grpN * 256 + g * 32 + row;
            float p2 = p2w[n * KK + k];
            float n1 = fmaxf(sqrtf(s1), EPS);
            float n2 = fmaxf(sqrtf(s2), EPS);
            float tot = dot / (n1 * n2) + p2 + bk;
            out[n * KK + k] = fmaxf(tot, 0.f);
        }
    }
}

extern "C" void kernel_launch(void* const* d_in, const int* in_sizes, int n_in,
                              void* d_out, int out_size, void* d_ws, size_t ws_size,
                              hipStream_t stream) {
    const float* x1 = (const float*)d_in[0];
    const float* x2 = (const float*)d_in[1];
    const float* W1 = (const float*)d_in[2];
    const float* W2 = (const float*)d_in[3];
    const float* V  = (const float*)d_in[4];
    const float* b  = (const float*)d_in[5];
    float* out = (float*)d_out;

    const int N = in_sizes[0] / DD;   // 32768

    __bf16* X1f = (__bf16*)d_ws;
    __bf16* X2f = X1f + (size_t)N * DD;
    __bf16* W1f = X2f + (size_t)N * DD;
    __bf16* W2f = W1f + (size_t)KK * DD * DD;
    float*  p2w = (float*)(W2f + (size_t)KK * DD * DD);

    const int cvt_half = N / 16;                  // 2048 blocks per tensor
    const int wf_half  = KK * DD * DD / 8 / 256;  // 256
    const int p2_blocks = N / 4;                  // 8192
    prep_kernel<<<2 * cvt_half + 2 * wf_half + p2_blocks, 256, 0, stream>>>(
        x1, x2, W1, W2, V, X1f, X2f, W1f, W2f, p2w, cvt_half, wf_half);

    const int groups = N / 256;                   // 128
    ntn_main<<<groups * KK, 256, 0, stream>>>(X1f, X2f, W1f, W2f, p2w, b, out,
                                              groups / 8);
}

// Round 15
// 169.166 us; speedup vs baseline: 2.0005x; 2.0005x over previous
//
#include <hip/hip_runtime.h>
#include <cstdint>
#include <cstddef>

#define DD 128
#define KK 32
constexpr float EPS = 1e-8f;

typedef __bf16 bf16x8 __attribute__((ext_vector_type(8)));
typedef float f32x4 __attribute__((ext_vector_type(4)));

__device__ __forceinline__ unsigned short f2bf(float x) {
    union { float f; uint32_t u; } v; v.f = x;
    uint32_t r = v.u + 0x7FFFu + ((v.u >> 16) & 1u);   // RNE
    return (unsigned short)(r >> 16);
}
__device__ __forceinline__ __bf16 f2bf16(float x) {
    unsigned short u = f2bf(x);
    __bf16 r; __builtin_memcpy(&r, &u, 2); return r;
}
// pack 8 floats -> 8 bf16 in a uint4 (one 16B store)
__device__ __forceinline__ uint4 pack8(float4 a, float4 b) {
    uint4 o;
    o.x = (uint32_t)f2bf(a.x) | ((uint32_t)f2bf(a.y) << 16);
    o.y = (uint32_t)f2bf(a.z) | ((uint32_t)f2bf(a.w) << 16);
    o.z = (uint32_t)f2bf(b.x) | ((uint32_t)f2bf(b.y) << 16);
    o.w = (uint32_t)f2bf(b.z) | ((uint32_t)f2bf(b.w) << 16);
    return o;
}

// DPP quad_perm fold over lane-xor 1,2 (VALU pipe, no LDS).
template <int CTRL>
__device__ __forceinline__ float dpp_fold(float x) {
    union { float f; int i; } u, r;
    u.f = x;
    r.i = __builtin_amdgcn_update_dpp(0, u.i, CTRL, 0xF, 0xF, false);
    return x + r.f;
}
__device__ __forceinline__ f32x4 fold4(f32x4 v) {
    #pragma unroll
    for (int c = 0; c < 4; ++c) {
        float x = v[c];
        x = dpp_fold<0xB1>(x);   // xor 1
        x = dpp_fold<0x4E>(x);   // xor 2
        v[c] = x;
    }
    return v;
}

// ---------------- prep kernel (r13 proven, verbatim): cvt + wf ---------------
// Xf[rg][c][mm][8]: row = rg*16+mm, d = c*8+j  -> off = rg*2048 + c*128 + mm*8
// Wf[k][eg][c][mm][8]: W[k][d=c*8+j][e=eg*16+mm]
__global__ __launch_bounds__(256) void prep_kernel(
    const float* __restrict__ x1, const float* __restrict__ x2,
    const float* __restrict__ W1, const float* __restrict__ W2,
    __bf16* __restrict__ X1f, __bf16* __restrict__ X2f,
    __bf16* __restrict__ W1f, __bf16* __restrict__ W2f,
    int cvt_half, int wf_half)
{
    __shared__ float tile[16][132];   // 8.4 KB, +4 pad
    int bb = blockIdx.x;
    if (bb < 2 * cvt_half) {
        const float* src; __bf16* dst;
        if (bb >= cvt_half) { src = x2; dst = X2f; bb -= cvt_half; }
        else                { src = x1; dst = X1f; }
        const int rg = bb;
        {
            const int row = threadIdx.x >> 4;
            const int c8  = (threadIdx.x & 15) * 8;
            const float* p = src + (size_t)(rg * 16 + row) * DD + c8;
            float4 f0 = *reinterpret_cast<const float4*>(p);
            float4 f1 = *reinterpret_cast<const float4*>(p + 4);
            *reinterpret_cast<float4*>(&tile[row][c8])     = f0;
            *reinterpret_cast<float4*>(&tile[row][c8 + 4]) = f1;
        }
        __syncthreads();
        {
            const int mm = threadIdx.x & 15;
            const int c  = threadIdx.x >> 4;
            float4 a = *reinterpret_cast<float4*>(&tile[mm][c * 8]);
            float4 b = *reinterpret_cast<float4*>(&tile[mm][c * 8 + 4]);
            size_t off = (size_t)rg * 2048 + (size_t)c * 128 + (size_t)mm * 8;
            *reinterpret_cast<uint4*>(dst + off) = pack8(a, b);
        }
    } else {
        bb -= 2 * cvt_half;
        const float* W; __bf16* Wf;
        if (bb >= wf_half) { W = W2; Wf = W2f; bb -= wf_half; }
        else               { W = W1; Wf = W1f; }
        int idx = bb * 256 + threadIdx.x;
        int mm = idx & 15;
        int c  = (idx >> 4) & 15;
        int eg = (idx >> 8) & 7;
        int k  = idx >> 11;
        const float* Wk = W + (size_t)k * DD * DD;
        int e = eg * 16 + mm;
        float4 a, b;
        a.x = Wk[(size_t)(c * 8 + 0) * DD + e];
        a.y = Wk[(size_t)(c * 8 + 1) * DD + e];
        a.z = Wk[(size_t)(c * 8 + 2) * DD + e];
        a.w = Wk[(size_t)(c * 8 + 3) * DD + e];
        b.x = Wk[(size_t)(c * 8 + 4) * DD + e];
        b.y = Wk[(size_t)(c * 8 + 5) * DD + e];
        b.z = Wk[(size_t)(c * 8 + 6) * DD + e];
        b.w = Wk[(size_t)(c * 8 + 7) * DD + e];
        size_t off = ((size_t)(k * 8 + eg)) * 2048 + (size_t)c * 128 + (size_t)mm * 8;
        *reinterpret_cast<uint4*>(Wf + off) = pack8(a, b);
    }
}

// ---------------- part2 GEMM (r11/r13 proven): p2w[n][k] = xcat[n].V[k] ------
__global__ __launch_bounds__(256) void part2_kernel(
    const __bf16* __restrict__ X1f, const __bf16* __restrict__ X2f,
    const float* __restrict__ V, float* __restrict__ p2w) {
    const int wave = threadIdx.x >> 6, lane = threadIdx.x & 63;
    const int m = lane & 15, quad = lane >> 4;
    const int rg0 = blockIdx.x * 16 + wave * 4;   // 64 rows per wave

    f32x4 acc[4][2];
    #pragma unroll
    for (int rt = 0; rt < 4; ++rt)
        #pragma unroll
        for (int ct = 0; ct < 2; ++ct) acc[rt][ct] = f32x4{0.f, 0.f, 0.f, 0.f};

    #pragma unroll
    for (int ks = 0; ks < 8; ++ks) {
        const __bf16* Xs = (ks < 4) ? X1f : X2f;
        const int kss = ks & 3;
        bf16x8 a[4];
        #pragma unroll
        for (int rt = 0; rt < 4; ++rt)
            a[rt] = *reinterpret_cast<const bf16x8*>(
                Xs + (size_t)(rg0 + rt) * 2048 + kss * 512 + lane * 8);
        #pragma unroll
        for (int ct = 0; ct < 2; ++ct) {
            const float* p = V + (size_t)(ct * 16 + m) * 256 + ks * 32 + quad * 8;
            float4 v0 = *reinterpret_cast<const float4*>(p);
            float4 v1 = *reinterpret_cast<const float4*>(p + 4);
            bf16x8 b;
            b[0] = f2bf16(v0.x); b[1] = f2bf16(v0.y); b[2] = f2bf16(v0.z); b[3] = f2bf16(v0.w);
            b[4] = f2bf16(v1.x); b[5] = f2bf16(v1.y); b[6] = f2bf16(v1.z); b[7] = f2bf16(v1.w);
            #pragma unroll
            for (int rt = 0; rt < 4; ++rt)
                acc[rt][ct] = __builtin_amdgcn_mfma_f32_16x16x32_bf16(a[rt], b, acc[rt][ct], 0, 0, 0);
        }
    }
    const int row0 = blockIdx.x * 256 + wave * 64;
    #pragma unroll
    for (int rt = 0; rt < 4; ++rt)
        #pragma unroll
        for (int ct = 0; ct < 2; ++ct)
            #pragma unroll
            for (int reg = 0; reg < 4; ++reg)
                p2w[(size_t)(row0 + rt * 16 + quad * 4 + reg) * KK + ct * 16 + m] = acc[rt][ct][reg];
}

// ---------------- main fused kernel: ONE barrier per block ------------------
// Grid 4096 = 32 k x 128 row-groups (256 rows). XCD decode: xcd=b&7,
// k=(b>>3)&31 fast, group per-XCD. Block = 4 waves, wave = (rh, eh):
// 16 rows x 64 cols of BOTH mats; B register-resident; A prefetched 1 tile
// ahead. Each tile's folded partials land in a per-tile LDS slice; a SINGLE
// __syncthreads after the whole g-loop lets waves drift (MFMA of one wave
// overlaps epilogue VALU of another), then all 256 threads emit all 256
// outputs. p2w value preloaded at kernel start (scatter fully hidden).
__global__ __launch_bounds__(256, 2) void ntn_main(
    const __bf16* __restrict__ X1f, const __bf16* __restrict__ X2f,
    const __bf16* __restrict__ W1f, const __bf16* __restrict__ W2f,
    const float* __restrict__ p2w, const float* __restrict__ bias,
    float* __restrict__ out, int grp_per_xcd)
{
    __shared__ __align__(16) float sRedAll[8][3][2][4][40];   // 30.7 KB

    const int b    = blockIdx.x;
    const int xcd  = b & 7;
    const int k    = (b >> 3) & 31;
    const int grpN = xcd * grp_per_xcd + (b >> 8);   // 256-row group
    const int tid  = threadIdx.x;
    const int wave = tid >> 6;
    const int lane = tid & 63;
    const int m    = lane & 15;
    const int quad = lane >> 4;
    const int rh   = wave & 1;      // row half of the 32-row tile
    const int eh   = wave >> 1;     // column half (64 cols)

    // ---- preload this thread's p2w value (n = grpN*256 + tid) ----
    const size_t nOut = (size_t)grpN * 256 + tid;
    const float p2v = p2w[nOut * KK + k];
    const float bk  = bias[k];

    const __bf16* W1p = W1f + (size_t)k * 16384;
    const __bf16* W2p = W2f + (size_t)k * 16384;

    // ---- cache BOTH B halves in registers: 2 mats x 4 ks x 4 et ----
    bf16x8 Bc[2][4][4];
    #pragma unroll
    for (int ks = 0; ks < 4; ++ks)
        #pragma unroll
        for (int et = 0; et < 4; ++et) {
            const size_t boff = (size_t)(eh * 4 + et) * 2048 + ks * 512 + lane * 8;
            Bc[0][ks][et] = *reinterpret_cast<const bf16x8*>(W1p + boff);
            Bc[1][ks][et] = *reinterpret_cast<const bf16x8*>(W2p + boff);
        }

    const int rg0 = grpN * 16;
    const size_t lane8 = (size_t)lane * 8;

    // ---- preload tile 0's A fragments ----
    bf16x8 a1[4], a2[4];
    {
        const size_t ab = (size_t)(rg0 + rh) * 2048 + lane8;
        #pragma unroll
        for (int ks = 0; ks < 4; ++ks) {
            a1[ks] = *reinterpret_cast<const bf16x8*>(X1f + ab + ks * 512);
            a2[ks] = *reinterpret_cast<const bf16x8*>(X2f + ab + ks * 512);
        }
    }

    #pragma unroll
    for (int g = 0; g < 8; ++g) {
        f32x4 acc[2][4];    // [mat][et]
        #pragma unroll
        for (int mat = 0; mat < 2; ++mat)
            #pragma unroll
            for (int et = 0; et < 4; ++et) acc[mat][et] = f32x4{0.f, 0.f, 0.f, 0.f};

        #pragma unroll
        for (int ks = 0; ks < 4; ++ks) {
            #pragma unroll
            for (int et = 0; et < 4; ++et) {
                acc[0][et] = __builtin_amdgcn_mfma_f32_16x16x32_bf16(a1[ks], Bc[0][ks][et], acc[0][et], 0, 0, 0);
                acc[1][et] = __builtin_amdgcn_mfma_f32_16x16x32_bf16(a2[ks], Bc[1][ks][et], acc[1][et], 0, 0, 0);
            }
        }

        // ---- prefetch tile g+1's A fragments ----
        if (g < 7) {
            const size_t ab = (size_t)(rg0 + (g + 1) * 2 + rh) * 2048 + lane8;
            #pragma unroll
            for (int ks = 0; ks < 4; ++ks) {
                a1[ks] = *reinterpret_cast<const bf16x8*>(X1f + ab + ks * 512);
                a2[ks] = *reinterpret_cast<const bf16x8*>(X2f + ab + ks * 512);
            }
        }

        // ---- in-register cross-mat products + DPP folds -> per-tile LDS ----
        f32x4 pd = {0.f, 0.f, 0.f, 0.f};
        f32x4 q1 = {0.f, 0.f, 0.f, 0.f};
        f32x4 q2 = {0.f, 0.f, 0.f, 0.f};
        #pragma unroll
        for (int et = 0; et < 4; ++et) {
            f32x4 c1 = acc[0][et];
            f32x4 c2 = acc[1][et];
            pd += c1 * c2;
            q1 += c1 * c1;
            q2 += c2 * c2;
        }
        pd = fold4(pd);
        q1 = fold4(q1);
        q2 = fold4(q2);

        if ((m & 3) == 0) {
            const int grp = m >> 2;
            const int rb  = rh * 16 + quad * 4;
            *reinterpret_cast<f32x4*>(&sRedAll[g][0][eh][grp][rb]) = pd;
            *reinterpret_cast<f32x4*>(&sRedAll[g][1][eh][grp][rb]) = q1;
            *reinterpret_cast<f32x4*>(&sRedAll[g][2][eh][grp][rb]) = q2;
        }
        // NO barrier here — waves drift through tiles independently.
    }

    __syncthreads();   // the ONLY barrier: all 8 tiles' partials visible

    // ---- output: thread t -> tile = t>>5, row = t&31 (n = grpN*256 + t) ----
    {
        const int tile = tid >> 5;
        const int row  = tid & 31;
        float dot = 0.f, s1 = 0.f, s2 = 0.f;
        #pragma unroll
        for (int e2 = 0; e2 < 2; ++e2)
            #pragma unroll
            for (int gg = 0; gg < 4; ++gg) {
                dot += sRedAll[tile][0][e2][gg][row];
                s1  += sRedAll[tile][1][e2][gg][row];
                s2  += sRedAll[tile][2][e2][gg][row];
            }
        float n1 = fmaxf(sqrtf(s1), EPS);
        float n2 = fmaxf(sqrtf(s2), EPS);
        float tot = dot / (n1 * n2) + p2v + bk;
        out[nOut * KK + k] = fmaxf(tot, 0.f);
    }
}

extern "C" void kernel_launch(void* const* d_in, const int* in_sizes, int n_in,
                              void* d_out, int out_size, void* d_ws, size_t ws_size,
                              hipStream_t stream) {
    const float* x1 = (const float*)d_in[0];
    const float* x2 = (const float*)d_in[1];
    const float* W1 = (const float*)d_in[2];
    const float* W2 = (const float*)d_in[3];
    const float* V  = (const float*)d_in[4];
    const float* b  = (const float*)d_in[5];
    float* out = (float*)d_out;

    const int N = in_sizes[0] / DD;   // 32768

    __bf16* X1f = (__bf16*)d_ws;
    __bf16* X2f = X1f + (size_t)N * DD;
    __bf16* W1f = X2f + (size_t)N * DD;
    __bf16* W2f = W1f + (size_t)KK * DD * DD;
    float*  p2w = (float*)(W2f + (size_t)KK * DD * DD);

    const int cvt_half = N / 16;                  // 2048 blocks per tensor
    const int wf_half  = KK * DD * DD / 8 / 256;  // 256
    prep_kernel<<<2 * cvt_half + 2 * wf_half, 256, 0, stream>>>(
        x1, x2, W1, W2, X1f, X2f, W1f, W2f, cvt_half, wf_half);

    part2_kernel<<<N / 256, 256, 0, stream>>>(X1f, X2f, V, p2w);

    const int groups = N / 256;                   // 128
    ntn_main<<<groups * KK, 256, 0, stream>>>(X1f, X2f, W1f, W2f, p2w, b, out,
                                              groups / 8);
}